// Round 1
// baseline (340.886 us; speedup 1.0000x reference)
//
#include <hip/hip_runtime.h>
#include <hip/hip_bf16.h>

typedef unsigned short u16;
typedef __bf16 bf16x8 __attribute__((ext_vector_type(8)));
typedef float f32x4 __attribute__((ext_vector_type(4)));

#define NTOK 32768   // B*S = 8*4096
#define DIM  512
#define KC   4096

__device__ __forceinline__ u16 f2b(float f) {
  __hip_bfloat16 h = __float2bfloat16(f);
  return *reinterpret_cast<u16*>(&h);
}

__device__ __forceinline__ void gload_lds16(const void* g, void* l) {
  __builtin_amdgcn_global_load_lds(
      (__attribute__((address_space(1))) void*)g,
      (__attribute__((address_space(3))) void*)l,
      16, 0, 0);
}

// ---------------- prep: fp32 -> bf16 conversion (8 elems/thread) -------------
__global__ void cvt8(const float* __restrict__ in, u16* __restrict__ out, int n8) {
  int i = blockIdx.x * blockDim.x + threadIdx.x;
  if (i >= n8) return;
  const float4* p = reinterpret_cast<const float4*>(in) + 2 * (size_t)i;
  float4 a = p[0], b = p[1];
  uint4 v;
  v.x = (unsigned)f2b(a.x) | ((unsigned)f2b(a.y) << 16);
  v.y = (unsigned)f2b(a.z) | ((unsigned)f2b(a.w) << 16);
  v.z = (unsigned)f2b(b.x) | ((unsigned)f2b(b.y) << 16);
  v.w = (unsigned)f2b(b.z) | ((unsigned)f2b(b.w) << 16);
  reinterpret_cast<uint4*>(out)[i] = v;
}

// codebook -> bf16, plus per-row squared L2 norm (fp32, exact)
__global__ void cvt_codebook(const float* __restrict__ cb, u16* __restrict__ cbb,
                             float* __restrict__ cnorm) {
  int k = blockIdx.x;          // 0..4095
  int t = threadIdx.x;         // 0..255
  float c0 = cb[(size_t)k * DIM + t];
  float c1 = cb[(size_t)k * DIM + 256 + t];
  cbb[(size_t)k * DIM + t]       = f2b(c0);
  cbb[(size_t)k * DIM + 256 + t] = f2b(c1);
  float s = c0 * c0 + c1 * c1;
#pragma unroll
  for (int m = 1; m < 64; m <<= 1) s += __shfl_xor(s, m, 64);
  __shared__ float w4[4];
  if ((t & 63) == 0) w4[t >> 6] = s;
  __syncthreads();
  if (t == 0) cnorm[k] = w4[0] + w4[1] + w4[2] + w4[3];
}

// ---------------- argmin GEMM: scores = cnorm[k] - 2 * x.c ------------------
// 128x128 tile, BK=64, 4 waves (2x2), mfma 16x16x32 bf16, global_load_lds w=16.
__global__ __launch_bounds__(256)
void argmin_gemm(const u16* __restrict__ Xb, const u16* __restrict__ Cb,
                 const float* __restrict__ cnorm,
                 float* __restrict__ pval, int* __restrict__ pidx) {
  __shared__ u16 As[128 * 64];
  __shared__ u16 Bs[128 * 64];
  __shared__ float rv[2][128];
  __shared__ int   ri[2][128];

  const int tid  = threadIdx.x;
  const int lane = tid & 63;
  const int wid  = tid >> 6;          // 0..3
  const int wr   = wid >> 1, wc = wid & 1;
  const int bm   = blockIdx.x;        // 0..255 token tiles
  const int bn   = blockIdx.y;        // 0..31  code tiles
  const int l15  = lane & 15, l4 = lane >> 4;
  const int srow = lane >> 3;         // 0..7 (staging)
  const int scol = (lane & 7) * 8;    // 0..56 (staging, elems)

  f32x4 acc[4][4];
#pragma unroll
  for (int i = 0; i < 4; i++)
#pragma unroll
    for (int j = 0; j < 4; j++)
#pragma unroll
      for (int r = 0; r < 4; r++) acc[i][j][r] = 0.f;

  for (int kk = 0; kk < DIM; kk += 64) {
#pragma unroll
    for (int i = 0; i < 4; i++) {
      int rA = (wid * 4 + i) * 8 + srow;   // 0..127
      gload_lds16(Xb + (size_t)(bm * 128 + rA) * DIM + kk + scol,
                  (void*)(As + (wid * 4 + i) * 512));
      gload_lds16(Cb + (size_t)(bn * 128 + rA) * DIM + kk + scol,
                  (void*)(Bs + (wid * 4 + i) * 512));
    }
    __syncthreads();
#pragma unroll
    for (int ks = 0; ks < 2; ks++) {
      bf16x8 af[4], bfr[4];
#pragma unroll
      for (int mi = 0; mi < 4; mi++) {
        int row = wr * 64 + mi * 16 + l15;
        af[mi] = *reinterpret_cast<const bf16x8*>(As + row * 64 + ks * 32 + l4 * 8);
      }
#pragma unroll
      for (int ni = 0; ni < 4; ni++) {
        int row = wc * 64 + ni * 16 + l15;
        bfr[ni] = *reinterpret_cast<const bf16x8*>(Bs + row * 64 + ks * 32 + l4 * 8);
      }
#pragma unroll
      for (int mi = 0; mi < 4; mi++)
#pragma unroll
        for (int ni = 0; ni < 4; ni++)
          acc[mi][ni] = __builtin_amdgcn_mfma_f32_16x16x32_bf16(
              af[mi], bfr[ni], acc[mi][ni], 0, 0, 0);
    }
    __syncthreads();
  }

  // epilogue: per-token argmin over this block's 128 codes
  float cn[4];
#pragma unroll
  for (int ni = 0; ni < 4; ni++)
    cn[ni] = cnorm[bn * 128 + wc * 64 + ni * 16 + l15];

#pragma unroll
  for (int mi = 0; mi < 4; mi++) {
#pragma unroll
    for (int r = 0; r < 4; r++) {
      float best = 1e30f;
      int bi = 0;
#pragma unroll
      for (int ni = 0; ni < 4; ni++) {
        float v = cn[ni] - 2.0f * acc[mi][ni][r];
        int code = bn * 128 + wc * 64 + ni * 16 + l15;
        if (v < best) { best = v; bi = code; }
      }
#pragma unroll
      for (int m = 1; m < 16; m <<= 1) {
        float ov = __shfl_xor(best, m, 64);
        int   oi = __shfl_xor(bi, m, 64);
        if (ov < best) { best = ov; bi = oi; }
      }
      if (l15 == 0) {
        int tloc = wr * 64 + mi * 16 + l4 * 4 + r;
        rv[wc][tloc] = best;
        ri[wc][tloc] = bi;
      }
    }
  }
  __syncthreads();
  if (tid < 128) {
    float v0 = rv[0][tid], v1 = rv[1][tid];
    int   i0 = ri[0][tid], i1 = ri[1][tid];
    float bv = v0; int bb = i0;
    if (v1 < bv) { bv = v1; bb = i1; }
    size_t g = (size_t)bn * NTOK + bm * 128 + tid;
    pval[g] = bv;
    pidx[g] = bb;
  }
}

__global__ void argmin_reduce(const float* __restrict__ pval, const int* __restrict__ pidx,
                              int* __restrict__ idx) {
  int t = blockIdx.x * 256 + threadIdx.x;   // 0..32767
  float best = 1e30f;
  int bi = 0;
  for (int c = 0; c < 32; c++) {
    float v = pval[(size_t)c * NTOK + t];
    if (v < best) { best = v; bi = pidx[(size_t)c * NTOK + t]; }
  }
  idx[t] = bi;
}

// ---------- gate GEMM (X @ W^T) + fused epilogue + deterministic loss -------
__global__ __launch_bounds__(256)
void gate_out(const u16* __restrict__ Xb, const u16* __restrict__ Wb,
              const float* __restrict__ X, const float* __restrict__ Cf,
              const float* __restrict__ gb, const int* __restrict__ idx,
              float* __restrict__ out, float* __restrict__ blockSum) {
  __shared__ u16 As[128 * 64];
  __shared__ u16 Bs[128 * 64];
  __shared__ float bsum[4];

  const int tid  = threadIdx.x;
  const int lane = tid & 63;
  const int wid  = tid >> 6;
  const int wr   = wid >> 1, wc = wid & 1;
  const int bm   = blockIdx.x;        // 0..255
  const int bn   = blockIdx.y;        // 0..3
  const int l15  = lane & 15, l4 = lane >> 4;
  const int srow = lane >> 3;
  const int scol = (lane & 7) * 8;

  f32x4 acc[4][4];
#pragma unroll
  for (int i = 0; i < 4; i++)
#pragma unroll
    for (int j = 0; j < 4; j++)
#pragma unroll
      for (int r = 0; r < 4; r++) acc[i][j][r] = 0.f;

  for (int kk = 0; kk < DIM; kk += 64) {
#pragma unroll
    for (int i = 0; i < 4; i++) {
      int rA = (wid * 4 + i) * 8 + srow;
      gload_lds16(Xb + (size_t)(bm * 128 + rA) * DIM + kk + scol,
                  (void*)(As + (wid * 4 + i) * 512));
      gload_lds16(Wb + (size_t)(bn * 128 + rA) * DIM + kk + scol,
                  (void*)(Bs + (wid * 4 + i) * 512));
    }
    __syncthreads();
#pragma unroll
    for (int ks = 0; ks < 2; ks++) {
      bf16x8 af[4], bfr[4];
#pragma unroll
      for (int mi = 0; mi < 4; mi++) {
        int row = wr * 64 + mi * 16 + l15;
        af[mi] = *reinterpret_cast<const bf16x8*>(As + row * 64 + ks * 32 + l4 * 8);
      }
#pragma unroll
      for (int ni = 0; ni < 4; ni++) {
        int row = wc * 64 + ni * 16 + l15;
        bfr[ni] = *reinterpret_cast<const bf16x8*>(Bs + row * 64 + ks * 32 + l4 * 8);
      }
#pragma unroll
      for (int mi = 0; mi < 4; mi++)
#pragma unroll
        for (int ni = 0; ni < 4; ni++)
          acc[mi][ni] = __builtin_amdgcn_mfma_f32_16x16x32_bf16(
              af[mi], bfr[ni], acc[mi][ni], 0, 0, 0);
    }
    __syncthreads();
  }

  // epilogue: gate = sigmoid(acc + b), out = x + c[idx]*gate, loss partial
  float lsum = 0.f;
#pragma unroll
  for (int mi = 0; mi < 4; mi++) {
#pragma unroll
    for (int r = 0; r < 4; r++) {
      int token = bm * 128 + wr * 64 + mi * 16 + l4 * 4 + r;
      int code = idx[token];
#pragma unroll
      for (int ni = 0; ni < 4; ni++) {
        int col = bn * 128 + wc * 64 + ni * 16 + l15;
        float logit = acc[mi][ni][r] + gb[col];
        float g = 1.0f / (1.0f + __expf(-logit));
        float q = Cf[(size_t)code * DIM + col];
        float xx = X[(size_t)token * DIM + col];
        out[(size_t)token * DIM + col] = xx + q * g;
        float d = q - xx;
        lsum += d * d;
      }
    }
  }
#pragma unroll
  for (int m = 1; m < 64; m <<= 1) lsum += __shfl_xor(lsum, m, 64);
  if (lane == 0) bsum[wid] = lsum;
  __syncthreads();
  if (tid == 0)
    blockSum[blockIdx.y * gridDim.x + blockIdx.x] = bsum[0] + bsum[1] + bsum[2] + bsum[3];
}

__global__ void finalize(const float* __restrict__ blockSum, float* __restrict__ out_loss) {
  int t = threadIdx.x;  // 256 threads, 1024 partials
  float s = 0.f;
#pragma unroll
  for (int i = 0; i < 4; i++) s += blockSum[t * 4 + i];
#pragma unroll
  for (int m = 1; m < 64; m <<= 1) s += __shfl_xor(s, m, 64);
  __shared__ float w4[4];
  if ((t & 63) == 0) w4[t >> 6] = s;
  __syncthreads();
  if (t == 0) {
    float tot = w4[0] + w4[1] + w4[2] + w4[3];
    out_loss[0] = 1.25f * tot / 16777216.0f;   // N*D = 32768*512
  }
}

extern "C" void kernel_launch(void* const* d_in, const int* in_sizes, int n_in,
                              void* d_out, int out_size, void* d_ws, size_t ws_size,
                              hipStream_t stream) {
  const float* X  = (const float*)d_in[0];   // [32768, 512]
  const float* CB = (const float*)d_in[1];   // [4096, 512]
  const float* GW = (const float*)d_in[2];   // [512, 512]
  const float* GB = (const float*)d_in[3];   // [512]
  float* out = (float*)d_out;                // [32768*512] output + [1] loss

  char* w = (char*)d_ws;
  size_t off = 0;
  auto alloc = [&](size_t bytes) -> void* {
    void* p = w + off;
    off = (off + bytes + 255) & ~(size_t)255;
    return p;
  };
  u16*   Xb    = (u16*)alloc((size_t)NTOK * DIM * 2);   // 33.5 MB
  u16*   Cb    = (u16*)alloc((size_t)KC * DIM * 2);     // 4.2 MB
  u16*   Wb    = (u16*)alloc((size_t)DIM * DIM * 2);    // 0.5 MB
  float* cnorm = (float*)alloc((size_t)KC * 4);
  float* pval  = (float*)alloc((size_t)32 * NTOK * 4);  // 4.2 MB
  int*   pidx  = (int*)alloc((size_t)32 * NTOK * 4);    // 4.2 MB
  int*   idx   = (int*)alloc((size_t)NTOK * 4);
  float* bsums = (float*)alloc((size_t)1024 * 4);

  cvt8<<<8192, 256, 0, stream>>>(X, Xb, NTOK * DIM / 8);
  cvt8<<<128, 256, 0, stream>>>(GW, Wb, DIM * DIM / 8);
  cvt_codebook<<<KC, 256, 0, stream>>>(CB, Cb, cnorm);
  argmin_gemm<<<dim3(256, 32), 256, 0, stream>>>(Xb, Cb, cnorm, pval, pidx);
  argmin_reduce<<<128, 256, 0, stream>>>(pval, pidx, idx);
  gate_out<<<dim3(256, 4), 256, 0, stream>>>(Xb, Wb, X, CB, GB, idx, out, bsums);
  finalize<<<1, 256, 0, stream>>>(bsums, out + (size_t)NTOK * DIM);
}